// Round 9
// baseline (192.905 us; speedup 1.0000x reference)
//
// r19b — resubmission of r19 (round-8 bench died to container infra, no
// kernel signal). Audited: all prefetches bounds-guarded, uniform barriers,
// same global extents as r18. Theory untested, unchanged:
// r18 post-mortem: 63us, clean gates, best so far. All 4096 waves resident;
// wall = per-wave chain = 151K cyc for ~3K inst (~50 cyc/inst); SIMDs idle
// 73%. ~220 VMEM/wave x ~600cyc = 132K: loads run near-serially. VGPR=64
// shows the allocator left no budget for loads-in-flight (A in AGPRs, B
// consumed immediately).
// r19: keep r18 skeleton; per layer, explicit ping-pong B pipeline with
// NAMED static buffers bA/bB (rule-20 safe): prologue ldb(ct0),ldb(ct1);
// loop: compute(bA) -> prefetch ct+2 into bA -> compute(bB) -> prefetch
// ct+3 -> ... steady ~8-16 loads in flight. Forced liveness ~150 regs ->
// launch_bounds(128,3) (cap ~170): 12 waves/CU instead of 16 — model says
// chain/2-3x beats waves-25%.
// Gates: FETCH ~62MB, WRITE ~33MB (growth = spill = invalid), VGPR 96-160.
// Predict: dur 63 -> 42-52us, MfmaUtil 17-21%. If unchanged: load-latency
// falsified -> ablate f2bf VALU next.
#include <hip/hip_runtime.h>

typedef __attribute__((ext_vector_type(8))) short short8;
typedef __attribute__((ext_vector_type(8))) unsigned short ushort8;
typedef __attribute__((ext_vector_type(4))) float f32x4;

#define MT 32            // batch rows per block (one slab)
#define STR 264          // bf16 elems per slab row: 256 + 8 pad (528B)

__device__ __forceinline__ float bmax_r19() { return __uint_as_float(0x7F7F0000u); }

// plain RTNE fp32 -> bf16 bits (pre-epilogue values provably finite/small).
__device__ __forceinline__ unsigned short f2bf_r19(float f) {
    unsigned int u = __float_as_uint(f);
    return (unsigned short)((u + 0x7fffu + ((u >> 16) & 1u)) >> 16);
}

// pack (unchanged, proven): one thread per 64-lane fragment slot.
// dst[(frag*64+lane)*8+j], frag=(n>>4)*8+(k>>5), lane=((k>>3)&3)*16+(n&15), j=k&7.
__global__ __launch_bounds__(256)
void pack_weights_r19(const float* __restrict__ W1,
                      const float* __restrict__ W2,
                      const float* __restrict__ W3,
                      unsigned short* __restrict__ ws) {
    int s = blockIdx.x * 256 + threadIdx.x;     // 80 x 256 = 20480 slots
    const float* src;
    unsigned short* dst;
    int N;
    if (s < 8192)       { src = W1; dst = ws;          N = 256; }
    else if (s < 16384) { src = W2; dst = ws + 65536;  N = 256; s -= 8192; }
    else                { src = W3; dst = ws + 131072; N = 128; s -= 16384; }
    int frag = s >> 6, lane = s & 63;
    int kb = (frag & 7) * 32 + (lane >> 4) * 8;   // k base (8 consecutive k)
    int n  = (frag >> 3) * 16 + (lane & 15);
    ushort8 o;
    #pragma unroll
    for (int j = 0; j < 8; ++j) o[j] = f2bf_r19(src[(kb + j) * N + n]);
    *(ushort8*)&dst[s * 8] = o;
}

// load the 8 k0-fragments of col-tile ctg into b[8] (8x dwordx4, independent)
__device__ __forceinline__ void ldb8_r19(short8 b[8],
                                         const unsigned short* __restrict__ wp,
                                         int ctg, int lane) {
    #pragma unroll
    for (int k0 = 0; k0 < 8; ++k0)
        b[k0] = *(const short8*)&wp[((ctg * 8 + k0) * 64 + lane) * 8];
}

// 16 MFMA for one ct using A-frags a0/a1 and B-frags b[8]
__device__ __forceinline__ void ct_mfma_r19(const short8 a0[8], const short8 a1[8],
                                            const short8 b[8], f32x4& ac0, f32x4& ac1) {
    #pragma unroll
    for (int k0 = 0; k0 < 8; ++k0) {
        ac0 = __builtin_amdgcn_mfma_f32_16x16x32_bf16(a0[k0], b[k0], ac0, 0, 0, 0);
        ac1 = __builtin_amdgcn_mfma_f32_16x16x32_bf16(a1[k0], b[k0], ac1, 0, 0, 0);
    }
}

__device__ __forceinline__ void ct_store_r19(unsigned short* __restrict__ act,
                                             const float* __restrict__ bias,
                                             int ctg, int quad, int noff,
                                             const f32x4& ac0, const f32x4& ac1) {
    const int col = ctg * 16 + noff;
    const float bv = bias[col];
    #pragma unroll
    for (int i = 0; i < 4; ++i) {
        act[(quad * 4 + i) * STR + col]      = f2bf_r19(fmaxf(ac0[i] + bv, 0.0f));
        act[(16 + quad * 4 + i) * STR + col] = f2bf_r19(fmaxf(ac1[i] + bv, 0.0f));
    }
}

// One 256-col layer for this wave: A-read + B-prologue BEFORE the barrier;
// pipelined ct loop (8 cts, depth-2 ping-pong) after. Caller supplies the
// trailing barrier.
__device__ __forceinline__ void layer_r19(unsigned short* __restrict__ act,
                                          const unsigned short* __restrict__ wp,
                                          const float* __restrict__ bias,
                                          int ctbase, int lane, int quad, int noff) {
    short8 a0[8], a1[8];
    #pragma unroll
    for (int k0 = 0; k0 < 8; ++k0) {
        a0[k0] = *(const short8*)&act[noff * STR + k0 * 32 + quad * 8];
        a1[k0] = *(const short8*)&act[(16 + noff) * STR + k0 * 32 + quad * 8];
    }
    short8 bA[8], bB[8];
    ldb8_r19(bA, wp, ctbase + 0, lane);
    ldb8_r19(bB, wp, ctbase + 1, lane);
    __syncthreads();   // both waves' A-reads done -> in-place stores safe
    #pragma unroll 1
    for (int pr = 0; pr < 4; ++pr) {
        const int ct0 = ctbase + 2 * pr;
        // even ct: compute with bA, then immediately refill bA for ct0+2
        f32x4 e0 = {}, e1 = {};
        ct_mfma_r19(a0, a1, bA, e0, e1);
        if (pr < 3) ldb8_r19(bA, wp, ct0 + 2, lane);   // in flight during odd ct
        ct_store_r19(act, bias, ct0, quad, noff, e0, e1);
        // odd ct: compute with bB, refill bB for ct0+3
        f32x4 o0 = {}, o1 = {};
        ct_mfma_r19(a0, a1, bB, o0, o1);
        if (pr < 3) ldb8_r19(bB, wp, ct0 + 3, lane);
        ct_store_r19(act, bias, ct0 + 1, quad, noff, o0, o1);
    }
}

__global__ __launch_bounds__(128, 3)   // cap ~170 regs; LDS 17KB -> 6-9 blk/CU
void ColorNetwork_32495722561720_kernel(
        const float* __restrict__ obs,
        const int* __restrict__ amask,
        const float* __restrict__ b1,
        const float* __restrict__ b2,
        const float* __restrict__ b3,
        const unsigned short* __restrict__ w1p,
        const unsigned short* __restrict__ w2p,
        const unsigned short* __restrict__ w3p,
        float* __restrict__ out)
{
    __shared__ __align__(16) unsigned short act[MT * STR];   // 16896 B
    __shared__ int rowany[MT];                               // 128 B

    const int tid  = threadIdx.x;
    const int wave = tid >> 6;          // 0..1 — owns col-tiles [wave*8, +8)
    const int lane = tid & 63;
    const int quad = lane >> 4;
    const int noff = lane & 15;
    const size_t rowbase = (size_t)blockIdx.x * MT;

    if (tid < MT) rowany[tid] = 0;

    // ---- stage: 32 rows x 256 fp32 -> bf16 slab (2048 float4, 16/thread) ----
    {
        const float4* xin = (const float4*)(obs + rowbase * 256);
        #pragma unroll 8
        for (int i = 0; i < 16; ++i) {
            int f = tid + i * 128;          // 64 float4-chunks per row
            int row = f >> 6;
            int c4 = f & 63;
            float4 v = xin[f];
            ushort4 p;
            p.x = f2bf_r19(v.x); p.y = f2bf_r19(v.y);
            p.z = f2bf_r19(v.z); p.w = f2bf_r19(v.w);
            *(ushort4*)&act[row * STR + c4 * 4] = p;
        }
    }
    __syncthreads();   // slab visible to both waves; rowany zeros before ORs

    // ---- rowany: 32 rows x 32 int4, 8/thread (both waves OR; race benign) ----
    {
        const int4* min4 = (const int4*)(amask + rowbase * 128);
        #pragma unroll 4
        for (int i = 0; i < 8; ++i) {
            int f = tid + i * 128;          // 32 int4 per row
            int4 m = min4[f];
            if (m.x | m.y | m.z | m.w) rowany[f >> 5] = 1;
        }
    }

    // ---- layer 1 (in place; layer_r19 contains the pre-store barrier,
    //      which also orders the rowany ORs above before the epilogue) ----
    layer_r19(act, w1p, b1, wave * 8, lane, quad, noff);
    __syncthreads();   // L1 writes visible

    // ---- layer 2 ----
    layer_r19(act, w2p, b2, wave * 8, lane, quad, noff);
    __syncthreads();   // L2 writes visible

    // ---- layer 3 (N=128): 4 cts/wave, same pipeline, no LDS stores ----
    {
        short8 a0[8], a1[8];
        #pragma unroll
        for (int k0 = 0; k0 < 8; ++k0) {
            a0[k0] = *(const short8*)&act[noff * STR + k0 * 32 + quad * 8];
            a1[k0] = *(const short8*)&act[(16 + noff) * STR + k0 * 32 + quad * 8];
        }
        const int ctbase = wave * 4;
        short8 bA[8], bB[8];
        ldb8_r19(bA, w3p, ctbase + 0, lane);
        ldb8_r19(bB, w3p, ctbase + 1, lane);

        int ra[8];   // this lane's rowany flags (barrier above ordered the ORs)
        #pragma unroll
        for (int rt = 0; rt < 2; ++rt)
            #pragma unroll
            for (int i = 0; i < 4; ++i)
                ra[rt * 4 + i] = rowany[rt * 16 + quad * 4 + i];

        const float BM = bmax_r19();
        #pragma unroll 1
        for (int pr = 0; pr < 2; ++pr) {
            #pragma unroll
            for (int half = 0; half < 2; ++half) {
                const int ct = ctbase + 2 * pr + half;
                f32x4 ac0 = {}, ac1 = {};
                if (half == 0) {
                    ct_mfma_r19(a0, a1, bA, ac0, ac1);
                    if (pr < 1) ldb8_r19(bA, w3p, ct + 2, lane);
                } else {
                    ct_mfma_r19(a0, a1, bB, ac0, ac1);
                    if (pr < 1) ldb8_r19(bB, w3p, ct + 2, lane);
                }
                const int col = ct * 16 + noff;
                const float bv = b3[col];
                #pragma unroll
                for (int rt = 0; rt < 2; ++rt) {
                    const f32x4& ac = rt ? ac1 : ac0;
                    #pragma unroll
                    for (int i = 0; i < 4; ++i) {
                        int row = rt * 16 + quad * 4 + i;
                        int m = amask[(rowbase + row) * 128 + col];   // L2/L3-hot
                        float v = ac[i] + bv;
                        v = fminf(fmaxf(v, -BM), BM);        // finite AND bf16-finite
                        if (!(v == v)) v = 0.0f;             // NaN scrub (paranoia)
                        if (!m) v = -BM;                     // FLOAT_MIN stand-in
                        if (!ra[rt * 4 + i]) v = (col == 0) ? 1.0f : -BM;
                        out[(rowbase + row) * 128 + col] = v;
                    }
                }
            }
        }
    }
}

extern "C" void kernel_launch(void* const* d_in, const int* in_sizes, int n_in,
                              void* d_out, int out_size, void* d_ws, size_t ws_size,
                              hipStream_t stream) {
    const float* obs   = (const float*)d_in[0];
    const int*   amask = (const int*)d_in[1];
    const float* W1 = (const float*)d_in[2];
    const float* b1 = (const float*)d_in[3];
    const float* W2 = (const float*)d_in[4];
    const float* b2 = (const float*)d_in[5];
    const float* W3 = (const float*)d_in[6];
    const float* b3 = (const float*)d_in[7];
    float* out = (float*)d_out;

    const int B = in_sizes[0] / 256;   // 65536 batch rows

    unsigned short* ws = (unsigned short*)d_ws;    // 163840 bf16 = 320 KB packed
    unsigned short* w1p = ws;
    unsigned short* w2p = ws + 65536;
    unsigned short* w3p = ws + 131072;

    pack_weights_r19<<<80, 256, 0, stream>>>(W1, W2, W3, ws);

    ColorNetwork_32495722561720_kernel<<<B / MT, 128, 0, stream>>>(
        obs, amask, b1, b2, b3, w1p, w2p, w3p, out);
}

// Round 10
// 182.974 us; speedup vs baseline: 1.0543x; 1.0543x over previous
//
// r20 — sync-domain = 1 wave at 16 waves/CU: row-split wave-private slabs.
// r19 post-mortem: 5th register-pipelining spill (VGPR 84, +19MB scratch
// WRITE, Occ 23%, 87us). Register-ILP family is dead.
// Clean-experiment table: r11 66 (8-wave domain) / r14 74 (4) / r18 63 (2) /
// r17 80 (1-wave but 8 waves/CU). Signal: smaller barrier domain wins IF
// waves/CU >= 16. r20 = domain 1 AND 16 waves/CU:
//  - wave owns 16 ROWS x all 256 cols (r18 split cols; rows make the slab
//    wave-private). A-frags for 16 rows = 8 short8 = 32 VGPR, held per
//    layer; in-place half-slab safe by within-wave program order.
//  - ZERO __syncthreads. 128-thr blocks, 17KB LDS -> 8 blocks/CU (grid-
//    capped) = 16 waves/CU, all mutually independent.
//  - cost: B-stream doubles (each wave reads full W): 1.31GB L2 ~ 38% of
//    L2 ceiling (43us floor) — acceptable.
//  - no forced liveness: b[8] loaded per ct, consumed immediately (r19
//    lesson); ct-loop unroll 2 like r18.
// Gates: FETCH 62-68MB, WRITE ~33MB, VGPR 90-112, 0 barriers.
// Predict: dur 63 -> 48-56us. If >=60 clean: domain lever exhausted ->
// latency-structural plateau, evaluate ROOFLINE.
#include <hip/hip_runtime.h>

typedef __attribute__((ext_vector_type(8))) short short8;
typedef __attribute__((ext_vector_type(8))) unsigned short ushort8;
typedef __attribute__((ext_vector_type(4))) float f32x4;

#define MT 32            // batch rows per block (2 waves x 16 rows)
#define STR 264          // bf16 elems per slab row: 256 + 8 pad (528B)

__device__ __forceinline__ float bmax_r20() { return __uint_as_float(0x7F7F0000u); }

// plain RTNE fp32 -> bf16 bits (pre-epilogue values provably finite/small).
__device__ __forceinline__ unsigned short f2bf_r20(float f) {
    unsigned int u = __float_as_uint(f);
    return (unsigned short)((u + 0x7fffu + ((u >> 16) & 1u)) >> 16);
}

// pack (unchanged, proven): one thread per 64-lane fragment slot.
// dst[(frag*64+lane)*8+j], frag=(n>>4)*8+(k>>5), lane=((k>>3)&3)*16+(n&15), j=k&7.
__global__ __launch_bounds__(256)
void pack_weights_r20(const float* __restrict__ W1,
                      const float* __restrict__ W2,
                      const float* __restrict__ W3,
                      unsigned short* __restrict__ ws) {
    int s = blockIdx.x * 256 + threadIdx.x;     // 80 x 256 = 20480 slots
    const float* src;
    unsigned short* dst;
    int N;
    if (s < 8192)       { src = W1; dst = ws;          N = 256; }
    else if (s < 16384) { src = W2; dst = ws + 65536;  N = 256; s -= 8192; }
    else                { src = W3; dst = ws + 131072; N = 128; s -= 16384; }
    int frag = s >> 6, lane = s & 63;
    int kb = (frag & 7) * 32 + (lane >> 4) * 8;   // k base (8 consecutive k)
    int n  = (frag >> 3) * 16 + (lane & 15);
    ushort8 o;
    #pragma unroll
    for (int j = 0; j < 8; ++j) o[j] = f2bf_r20(src[(kb + j) * N + n]);
    *(ushort8*)&dst[s * 8] = o;
}

__global__ __launch_bounds__(128, 4)   // cap 128 regs; LDS 17KB; 8 blk/CU (grid)
void ColorNetwork_32495722561720_kernel(
        const float* __restrict__ obs,
        const int* __restrict__ amask,
        const float* __restrict__ b1,
        const float* __restrict__ b2,
        const float* __restrict__ b3,
        const unsigned short* __restrict__ w1p,
        const unsigned short* __restrict__ w2p,
        const unsigned short* __restrict__ w3p,
        float* __restrict__ out)
{
    // two wave-private 16-row half-slabs; NO cross-wave access anywhere
    __shared__ __align__(16) unsigned short act[MT * STR];   // 16896 B
    __shared__ int rowany[MT];                               // 128 B

    const int tid  = threadIdx.x;
    const int wave = tid >> 6;          // 0..1 — owns rows [wave*16, +16)
    const int lane = tid & 63;
    const int quad = lane >> 4;
    const int noff = lane & 15;
    const size_t rowbase = (size_t)blockIdx.x * MT + (size_t)wave * 16;
    const int sb = wave * 16 * STR;     // this wave's half-slab base
    const int rb = wave * 16;           // this wave's rowany base

    // ---- stage own 16 rows: 1024 float4/wave, 16/lane, coalesced ----
    {
        const float4* xin = (const float4*)(obs + rowbase * 256);
        #pragma unroll 4
        for (int i = 0; i < 16; ++i) {
            int f = lane + i * 64;          // 64 float4-chunks per row
            int row = f >> 6;               // local row 0..15
            int c4 = f & 63;
            float4 v = xin[f];
            ushort4 p;
            p.x = f2bf_r20(v.x); p.y = f2bf_r20(v.y);
            p.z = f2bf_r20(v.z); p.w = f2bf_r20(v.w);
            *(ushort4*)&act[sb + row * STR + c4 * 4] = p;
        }
    }

    // ---- rowany for own 16 rows (wave-private; program order suffices) ----
    if (lane < 16) rowany[rb + lane] = 0;
    {
        const int4* min4 = (const int4*)(amask + rowbase * 128);
        #pragma unroll 4
        for (int i = 0; i < 8; ++i) {
            int f = lane + i * 64;          // 16 rows x 32 int4 = 512
            int4 m = min4[f];
            if (m.x | m.y | m.z | m.w) rowany[rb + (f >> 5)] = 1;  // same-wave race: all write 1
        }
    }

    short8 a[8];   // A-frags of own 16 rows (32 VGPR, held per layer)

    // ================= layer 1: half-slab -> regs -> MFMA(w1p) -> half-slab =================
    #pragma unroll
    for (int k0 = 0; k0 < 8; ++k0)
        a[k0] = *(const short8*)&act[sb + noff * STR + k0 * 32 + quad * 8];
    #pragma unroll 2
    for (int ct = 0; ct < 16; ++ct) {
        f32x4 acc = {};
        #pragma unroll
        for (int k0 = 0; k0 < 8; ++k0) {
            short8 b = *(const short8*)&w1p[((ct * 8 + k0) * 64 + lane) * 8];
            acc = __builtin_amdgcn_mfma_f32_16x16x32_bf16(a[k0], b, acc, 0, 0, 0);
        }
        const int col = ct * 16 + noff;
        const float bv = b1[col];
        #pragma unroll
        for (int i = 0; i < 4; ++i)
            act[sb + (quad * 4 + i) * STR + col] = f2bf_r20(fmaxf(acc[i] + bv, 0.0f));
    }

    // ================= layer 2: same with w2p =================
    #pragma unroll
    for (int k0 = 0; k0 < 8; ++k0)
        a[k0] = *(const short8*)&act[sb + noff * STR + k0 * 32 + quad * 8];
    #pragma unroll 2
    for (int ct = 0; ct < 16; ++ct) {
        f32x4 acc = {};
        #pragma unroll
        for (int k0 = 0; k0 < 8; ++k0) {
            short8 b = *(const short8*)&w2p[((ct * 8 + k0) * 64 + lane) * 8];
            acc = __builtin_amdgcn_mfma_f32_16x16x32_bf16(a[k0], b, acc, 0, 0, 0);
        }
        const int col = ct * 16 + noff;
        const float bv = b2[col];
        #pragma unroll
        for (int i = 0; i < 4; ++i)
            act[sb + (quad * 4 + i) * STR + col] = f2bf_r20(fmaxf(acc[i] + bv, 0.0f));
    }

    // ================= layer 3 (N=128): 8 cts, masked fp32 store =================
    #pragma unroll
    for (int k0 = 0; k0 < 8; ++k0)
        a[k0] = *(const short8*)&act[sb + noff * STR + k0 * 32 + quad * 8];

    int ra[4];   // this lane's 4 rows' flags (own half; program order)
    #pragma unroll
    for (int i = 0; i < 4; ++i) ra[i] = rowany[rb + quad * 4 + i];

    const float BM = bmax_r20();
    #pragma unroll 2
    for (int ct = 0; ct < 8; ++ct) {
        f32x4 acc = {};
        #pragma unroll
        for (int k0 = 0; k0 < 8; ++k0) {
            short8 b = *(const short8*)&w3p[((ct * 8 + k0) * 64 + lane) * 8];
            acc = __builtin_amdgcn_mfma_f32_16x16x32_bf16(a[k0], b, acc, 0, 0, 0);
        }
        const int col = ct * 16 + noff;
        const float bv = b3[col];
        #pragma unroll
        for (int i = 0; i < 4; ++i) {
            int row = quad * 4 + i;                       // local row in own 16
            int m = amask[(rowbase + row) * 128 + col];   // L2/L3-hot (rowany pass)
            float v = acc[i] + bv;
            v = fminf(fmaxf(v, -BM), BM);        // finite AND bf16-finite
            if (!(v == v)) v = 0.0f;             // NaN scrub (paranoia)
            if (!m) v = -BM;                     // FLOAT_MIN stand-in
            if (!ra[i]) v = (col == 0) ? 1.0f : -BM;
            out[(rowbase + row) * 128 + col] = v;
        }
    }
}

extern "C" void kernel_launch(void* const* d_in, const int* in_sizes, int n_in,
                              void* d_out, int out_size, void* d_ws, size_t ws_size,
                              hipStream_t stream) {
    const float* obs   = (const float*)d_in[0];
    const int*   amask = (const int*)d_in[1];
    const float* W1 = (const float*)d_in[2];
    const float* b1 = (const float*)d_in[3];
    const float* W2 = (const float*)d_in[4];
    const float* b2 = (const float*)d_in[5];
    const float* W3 = (const float*)d_in[6];
    const float* b3 = (const float*)d_in[7];
    float* out = (float*)d_out;

    const int B = in_sizes[0] / 256;   // 65536 batch rows

    unsigned short* ws = (unsigned short*)d_ws;    // 163840 bf16 = 320 KB packed
    unsigned short* w1p = ws;
    unsigned short* w2p = ws + 65536;
    unsigned short* w3p = ws + 131072;

    pack_weights_r20<<<80, 256, 0, stream>>>(W1, W2, W3, ws);

    ColorNetwork_32495722561720_kernel<<<B / MT, 128, 0, stream>>>(
        obs, amask, b1, b2, b3, w1p, w2p, w3p, out);
}

// Round 11
// 159.230 us; speedup vs baseline: 1.2115x; 1.1491x over previous
//
// r21 — weight-stationary waves: B-frags loaded ONCE per layer into regs,
// swept over 4 row-chunks. Attack = per-wave VMEM chain (the only variable
// that tracks the wall across r11/r17/r18/r20: r20 doubled per-wave
// B-stream -> +18us; all designs re-stream W per 32-64 rows).
//  - 512 thr / 8 waves, MT=64 rows, TWO slabs: L1 A->B, L2 B->A, L3 reads A
//    (out-of-place => no intra-layer hazard, 3 barriers total).
//  - per layer: wave owns 2 col-tiles; 16 B-frags = 64 VGPR READ-ONLY
//    residency (r18's A-frag pattern, not r19's rotating-prefetch WAR) —
//    loaded BEFORE the barrier to hide latency under the wait.
//  - per-wave B-loads 168 -> 40; VMEM ~220 -> ~85; L2 B-traffic 655->328MB.
//  - LDS 67.8KB -> 2 blocks/CU = 16 waves/CU; 1024 blocks = 2 clean rounds.
//  - chunk loop unroll 1 (contain liveness ~115 < 128 cap (512,4)).
//  - direct __shared__ symbol indexing only (r16 lesson).
// Gates: FETCH 62-66MB, WRITE ~33MB, VGPR<=128, LDS ~68KB.
// Predict: dur 63 -> 38-50us, MfmaUtil 18-28%. If >=60 clean: VMEM-count
// falsified -> profile LDS/issue, plateau likely.
#include <hip/hip_runtime.h>

typedef __attribute__((ext_vector_type(8))) short short8;
typedef __attribute__((ext_vector_type(8))) unsigned short ushort8;
typedef __attribute__((ext_vector_type(4))) float f32x4;

#define MT 64            // batch rows per block
#define STR 264          // bf16 elems per slab row: 256 + 8 pad (528B)

__device__ __forceinline__ float bmax_r21() { return __uint_as_float(0x7F7F0000u); }

// plain RTNE fp32 -> bf16 bits (pre-epilogue values provably finite/small).
__device__ __forceinline__ unsigned short f2bf_r21(float f) {
    unsigned int u = __float_as_uint(f);
    return (unsigned short)((u + 0x7fffu + ((u >> 16) & 1u)) >> 16);
}

// pack (unchanged, proven): one thread per 64-lane fragment slot.
// dst[(frag*64+lane)*8+j], frag=(n>>4)*8+(k>>5), lane=((k>>3)&3)*16+(n&15), j=k&7.
__global__ __launch_bounds__(256)
void pack_weights_r21(const float* __restrict__ W1,
                      const float* __restrict__ W2,
                      const float* __restrict__ W3,
                      unsigned short* __restrict__ ws) {
    int s = blockIdx.x * 256 + threadIdx.x;     // 80 x 256 = 20480 slots
    const float* src;
    unsigned short* dst;
    int N;
    if (s < 8192)       { src = W1; dst = ws;          N = 256; }
    else if (s < 16384) { src = W2; dst = ws + 65536;  N = 256; s -= 8192; }
    else                { src = W3; dst = ws + 131072; N = 128; s -= 16384; }
    int frag = s >> 6, lane = s & 63;
    int kb = (frag & 7) * 32 + (lane >> 4) * 8;   // k base (8 consecutive k)
    int n  = (frag >> 3) * 16 + (lane & 15);
    ushort8 o;
    #pragma unroll
    for (int j = 0; j < 8; ++j) o[j] = f2bf_r21(src[(kb + j) * N + n]);
    *(ushort8*)&dst[s * 8] = o;
}

__global__ __launch_bounds__(512, 4)   // cap 128 regs; LDS 67.8KB -> 2 blk/CU
void ColorNetwork_32495722561720_kernel(
        const float* __restrict__ obs,
        const int* __restrict__ amask,
        const float* __restrict__ b1,
        const float* __restrict__ b2,
        const float* __restrict__ b3,
        const unsigned short* __restrict__ w1p,
        const unsigned short* __restrict__ w2p,
        const unsigned short* __restrict__ w3p,
        float* __restrict__ out)
{
    __shared__ __align__(16) unsigned short slabA[MT * STR];   // 33792 B
    __shared__ __align__(16) unsigned short slabB[MT * STR];   // 33792 B
    __shared__ int rowany[MT];                                 // 256 B

    const int tid  = threadIdx.x;
    const int wave = tid >> 6;          // 0..7
    const int lane = tid & 63;
    const int quad = lane >> 4;
    const int noff = lane & 15;
    const size_t rowbase = (size_t)blockIdx.x * MT;

    if (tid < MT) rowany[tid] = 0;

    // ---- stage: 64 rows x 256 fp32 -> bf16 slabA (4096 float4, 8/thread) ----
    {
        const float4* xin = (const float4*)(obs + rowbase * 256);
        #pragma unroll
        for (int i = 0; i < 8; ++i) {
            int f = tid + i * 512;          // 64 float4-chunks per row
            int row = f >> 6;
            int c4 = f & 63;
            float4 v = xin[f];
            ushort4 p;
            p.x = f2bf_r21(v.x); p.y = f2bf_r21(v.y);
            p.z = f2bf_r21(v.z); p.w = f2bf_r21(v.w);
            *(ushort4*)&slabA[row * STR + c4 * 4] = p;
        }
    }

    // ---- layer-1 B-frags: 2 col-tiles, 16 short8 = 64 VGPR, read-only ----
    // issued BEFORE the barrier: latency hides under the barrier wait.
    short8 bA[8], bB[8];
    {
        const int c0 = wave * 2, c1 = wave * 2 + 1;
        #pragma unroll
        for (int k0 = 0; k0 < 8; ++k0) {
            bA[k0] = *(const short8*)&w1p[((c0 * 8 + k0) * 64 + lane) * 8];
            bB[k0] = *(const short8*)&w1p[((c1 * 8 + k0) * 64 + lane) * 8];
        }
    }
    __syncthreads();   // bar1: slabA + rowany zeros visible

    // ---- rowany ORs (in L1 phase: independent VMEM, overlaps MFMA; zeros
    //      ordered by bar1; readers after bar3) ----
    {
        const int4* min4 = (const int4*)(amask + rowbase * 128);
        #pragma unroll
        for (int i = 0; i < 4; ++i) {
            int f = tid + i * 512;          // 32 int4 per row
            int4 m = min4[f];
            if (m.x | m.y | m.z | m.w) rowany[f >> 5] = 1;
        }
    }

    {   // ---- layer 1: slabA -> slabB, B stationary across 4 chunks ----
        const int col0 = (wave * 2) * 16 + noff;
        const float bv0 = b1[col0], bv1 = b1[col0 + 16];
        #pragma unroll 1
        for (int r = 0; r < 4; ++r) {
            short8 a[8];
            #pragma unroll
            for (int k0 = 0; k0 < 8; ++k0)
                a[k0] = *(const short8*)&slabA[(r * 16 + noff) * STR + k0 * 32 + quad * 8];
            f32x4 ac0 = {}, ac1 = {};
            #pragma unroll
            for (int k0 = 0; k0 < 8; ++k0) {
                ac0 = __builtin_amdgcn_mfma_f32_16x16x32_bf16(a[k0], bA[k0], ac0, 0, 0, 0);
                ac1 = __builtin_amdgcn_mfma_f32_16x16x32_bf16(a[k0], bB[k0], ac1, 0, 0, 0);
            }
            #pragma unroll
            for (int i = 0; i < 4; ++i) {
                int rw = (r * 16 + quad * 4 + i) * STR;
                slabB[rw + col0]      = f2bf_r21(fmaxf(ac0[i] + bv0, 0.0f));
                slabB[rw + col0 + 16] = f2bf_r21(fmaxf(ac1[i] + bv1, 0.0f));
            }
        }
    }
    // layer-2 B-frags issued before the barrier (hide under wait)
    {
        const int c0 = wave * 2, c1 = wave * 2 + 1;
        #pragma unroll
        for (int k0 = 0; k0 < 8; ++k0) {
            bA[k0] = *(const short8*)&w2p[((c0 * 8 + k0) * 64 + lane) * 8];
            bB[k0] = *(const short8*)&w2p[((c1 * 8 + k0) * 64 + lane) * 8];
        }
    }
    __syncthreads();   // bar2: slabB complete

    {   // ---- layer 2: slabB -> slabA ----
        const int col0 = (wave * 2) * 16 + noff;
        const float bv0 = b2[col0], bv1 = b2[col0 + 16];
        #pragma unroll 1
        for (int r = 0; r < 4; ++r) {
            short8 a[8];
            #pragma unroll
            for (int k0 = 0; k0 < 8; ++k0)
                a[k0] = *(const short8*)&slabB[(r * 16 + noff) * STR + k0 * 32 + quad * 8];
            f32x4 ac0 = {}, ac1 = {};
            #pragma unroll
            for (int k0 = 0; k0 < 8; ++k0) {
                ac0 = __builtin_amdgcn_mfma_f32_16x16x32_bf16(a[k0], bA[k0], ac0, 0, 0, 0);
                ac1 = __builtin_amdgcn_mfma_f32_16x16x32_bf16(a[k0], bB[k0], ac1, 0, 0, 0);
            }
            #pragma unroll
            for (int i = 0; i < 4; ++i) {
                int rw = (r * 16 + quad * 4 + i) * STR;
                slabA[rw + col0]      = f2bf_r21(fmaxf(ac0[i] + bv0, 0.0f));
                slabA[rw + col0 + 16] = f2bf_r21(fmaxf(ac1[i] + bv1, 0.0f));
            }
        }
    }
    // layer-3 B-frags: wave owns ONE col-tile (ct = wave), 8 short8
    {
        #pragma unroll
        for (int k0 = 0; k0 < 8; ++k0)
            bA[k0] = *(const short8*)&w3p[((wave * 8 + k0) * 64 + lane) * 8];
    }
    __syncthreads();   // bar3: slabA complete; rowany ORs complete (bar2)

    {   // ---- layer 3 (N=128): slabA -> masked fp32 out, B stationary ----
        const int col = wave * 16 + noff;
        const float bv = b3[col];
        const float BM = bmax_r21();
        #pragma unroll 1
        for (int r = 0; r < 4; ++r) {
            short8 a[8];
            #pragma unroll
            for (int k0 = 0; k0 < 8; ++k0)
                a[k0] = *(const short8*)&slabA[(r * 16 + noff) * STR + k0 * 32 + quad * 8];
            f32x4 acc = {};
            #pragma unroll
            for (int k0 = 0; k0 < 8; ++k0)
                acc = __builtin_amdgcn_mfma_f32_16x16x32_bf16(a[k0], bA[k0], acc, 0, 0, 0);
            #pragma unroll
            for (int i = 0; i < 4; ++i) {
                int row = r * 16 + quad * 4 + i;
                int m = amask[(rowbase + row) * 128 + col];   // L2/L3-hot
                float v = acc[i] + bv;
                v = fminf(fmaxf(v, -BM), BM);        // finite AND bf16-finite
                if (!(v == v)) v = 0.0f;             // NaN scrub (paranoia)
                if (!m) v = -BM;                     // FLOAT_MIN stand-in
                if (!rowany[row]) v = (col == 0) ? 1.0f : -BM;
                out[(rowbase + row) * 128 + col] = v;
            }
        }
    }
}

extern "C" void kernel_launch(void* const* d_in, const int* in_sizes, int n_in,
                              void* d_out, int out_size, void* d_ws, size_t ws_size,
                              hipStream_t stream) {
    const float* obs   = (const float*)d_in[0];
    const int*   amask = (const int*)d_in[1];
    const float* W1 = (const float*)d_in[2];
    const float* b1 = (const float*)d_in[3];
    const float* W2 = (const float*)d_in[4];
    const float* b2 = (const float*)d_in[5];
    const float* W3 = (const float*)d_in[6];
    const float* b3 = (const float*)d_in[7];
    float* out = (float*)d_out;

    const int B = in_sizes[0] / 256;   // 65536 batch rows

    unsigned short* ws = (unsigned short*)d_ws;    // 163840 bf16 = 320 KB packed
    unsigned short* w1p = ws;
    unsigned short* w2p = ws + 65536;
    unsigned short* w3p = ws + 131072;

    pack_weights_r21<<<80, 256, 0, stream>>>(W1, W2, W3, ws);

    ColorNetwork_32495722561720_kernel<<<B / MT, 512, 0, stream>>>(
        obs, amask, b1, b2, b3, w1p, w2p, w3p, out);
}